// Round 1
// baseline (371.001 us; speedup 1.0000x reference)
//
#include <hip/hip_runtime.h>

// Perceive3D: x (B=4, C=16, D=64, H=64, W=64) fp32, edge-padded 3^3 stencil
// with 4 separable kernels (identity, sobel-x(W), sobel-y(H), sobel-z(D)).
// Output layout (B, 4, C, D, H, W) flattened to (B, 4*C, D, H, W).
//
// Memory-bound: 64 MB in + 256 MB out => ~51 us floor at 6.3 TB/s.

#define B_ 4
#define C_ 16
#define D_ 64
#define H_ 64
#define W_ 64

__global__ __launch_bounds__(256) void perceive3d_kernel(
    const float* __restrict__ x, float* __restrict__ out)
{
    const int w  = threadIdx.x;                       // 0..63
    const int h  = blockIdx.x * blockDim.y + threadIdx.y;
    const int d  = blockIdx.y;
    const int bc = blockIdx.z;                        // b*C + c
    const int b  = bc >> 4;
    const int c  = bc & 15;

    const int wm = (w == 0)      ? 0        : w - 1;
    const int wp = (w == W_ - 1) ? (W_ - 1) : w + 1;

    const float* xb = x + (size_t)bc * (D_ * H_ * W_);

    float sW[3][3];   // row smoothed along W:  a[-1] + 2a[0] + a[+1]
    float dW[3][3];   // row diff along W:      a[+1] - a[-1]
    float center = 0.0f;

#pragma unroll
    for (int i = 0; i < 3; ++i) {
        int dz = d + i - 1;
        dz = (dz < 0) ? 0 : ((dz > D_ - 1) ? D_ - 1 : dz);
#pragma unroll
        for (int j = 0; j < 3; ++j) {
            int hy = h + j - 1;
            hy = (hy < 0) ? 0 : ((hy > H_ - 1) ? H_ - 1 : hy);
            const float* row = xb + ((size_t)dz * H_ + hy) * W_;
            float am = row[wm];
            float ac = row[w];
            float ap = row[wp];
            sW[i][j] = am + 2.0f * ac + ap;
            dW[i][j] = ap - am;
            if (i == 1 && j == 1) center = ac;
        }
    }

    const float sx = ( (dW[0][0] + 2.0f * dW[0][1] + dW[0][2])
            + 2.0f * (dW[1][0] + 2.0f * dW[1][1] + dW[1][2])
            +        (dW[2][0] + 2.0f * dW[2][1] + dW[2][2]) ) * (1.0f / 16.0f);

    const float sy = (        (sW[0][2] - sW[0][0])
                     + 2.0f * (sW[1][2] - sW[1][0])
                     +        (sW[2][2] - sW[2][0]) ) * (1.0f / 16.0f);

    const float sz = (        (sW[2][0] - sW[0][0])
                     + 2.0f * (sW[2][1] - sW[0][1])
                     +        (sW[2][2] - sW[0][2]) ) * (1.0f / 16.0f);

    const size_t dhw     = (size_t)D_ * H_ * W_;
    const size_t spatial = ((size_t)d * H_ + h) * W_ + w;
    const size_t cdhw    = (size_t)C_ * dhw;     // stride between kernel slots k

    float* o = out + ((size_t)(b * 4) * C_ + c) * dhw + spatial;
    o[0 * cdhw] = center;   // identity
    o[1 * cdhw] = sx;       // d/dW
    o[2 * cdhw] = sy;       // d/dH
    o[3 * cdhw] = sz;       // d/dD
}

extern "C" void kernel_launch(void* const* d_in, const int* in_sizes, int n_in,
                              void* d_out, int out_size, void* d_ws, size_t ws_size,
                              hipStream_t stream) {
    (void)in_sizes; (void)n_in; (void)d_ws; (void)ws_size; (void)out_size;
    const float* x = (const float*)d_in[0];
    // d_in[1] (kernels) is deterministic per the reference; coefficients are
    // hard-coded in the separable stencil above.
    float* out = (float*)d_out;

    dim3 block(W_, 4, 1);                 // 256 threads, lanes along W (coalesced)
    dim3 grid(H_ / 4, D_, B_ * C_);       // 16 x 64 x 64 = 65536 blocks
    perceive3d_kernel<<<grid, block, 0, stream>>>(x, out);
}

// Round 2
// 315.309 us; speedup vs baseline: 1.1766x; 1.1766x over previous
//
#include <hip/hip_runtime.h>

// Perceive3D: x (B=4, C=16, D=64, H=64, W=64) fp32, edge-padded 3^3 stencil,
// 4 separable kernels (identity, sobel-W, sobel-H, sobel-D), out (B,4,C,D,H,W).
//
// R2: float4-per-thread along W. Each 16-lane group owns one (d,h) row of 64
// floats; +-1 shifted vectors built from 2 shuffles/row instead of extra
// loads. 9 dwordx4 loads + 4 dwordx4 nontemporal stores per thread.
// Memory floor: 64 MB in + 268 MB out => ~53 us at 6.3 TB/s.

#define B_ 4
#define C_ 16
#define D_ 64
#define H_ 64
#define W_ 64

typedef float float4v __attribute__((ext_vector_type(4)));

__global__ __launch_bounds__(256) void perceive3d_kernel(
    const float* __restrict__ x, float* __restrict__ out)
{
    const int lane = threadIdx.x;          // 0..63
    const int quad = lane & 15;            // w = 4*quad
    const int hsub = lane >> 4;            // 0..3
    const int h    = blockIdx.x * 16 + threadIdx.y * 4 + hsub;
    const int d    = blockIdx.y;
    const int bc   = blockIdx.z;           // b*C + c
    const int b    = bc >> 4;
    const int c    = bc & 15;

    const float* xb = x + (size_t)bc * (D_ * H_ * W_);

    const int dm = (d == 0) ? 0 : d - 1;
    const int dp = (d == D_ - 1) ? D_ - 1 : d + 1;
    const int hm = (h == 0) ? 0 : h - 1;
    const int hp = (h == H_ - 1) ? H_ - 1 : h + 1;

    const int dzo[3] = { dm * (H_ * W_), d * (H_ * W_), dp * (H_ * W_) };
    const int hyo[3] = { hm * W_,        h * W_,        hp * W_ };
    const float si[3] = { 1.0f, 2.0f, 1.0f };

    float4v sx = {0,0,0,0}, sy = {0,0,0,0}, sz = {0,0,0,0};
    float4v center = {0,0,0,0};

#pragma unroll
    for (int i = 0; i < 3; ++i) {
#pragma unroll
        for (int j = 0; j < 3; ++j) {
            const float* row = xb + dzo[i] + hyo[j];
            float4v q = *(const float4v*)(row + 4 * quad);

            // +-1 shifted vectors via cross-lane; quad 0/15 edge-clamp.
            float left  = __shfl_up(q.w, 1);
            float right = __shfl_down(q.x, 1);
            if (quad == 0)      left  = q.x;   // w=-1 -> clamp to w=0
            if (quad == 15)     right = q.w;   // w=64 -> clamp to w=63

            float4v am = { left, q.x, q.y, q.z };   // x[w-1]
            float4v ap = { q.y, q.z, q.w, right };  // x[w+1]

            float4v sw = am + 2.0f * q + ap;        // smooth along W
            float4v dw = ap - am;                   // diff along W

            const float cij = si[i] * si[j];
            sx += cij * dw;
            if (j == 0)      sy -= si[i] * sw;
            else if (j == 2) sy += si[i] * sw;
            if (i == 0)      sz -= si[j] * sw;
            else if (i == 2) sz += si[j] * sw;
            if (i == 1 && j == 1) center = q;
        }
    }

    sx *= (1.0f / 16.0f);
    sy *= (1.0f / 16.0f);
    sz *= (1.0f / 16.0f);

    const size_t dhw     = (size_t)D_ * H_ * W_;
    const size_t cdhw    = (size_t)C_ * dhw;     // stride between kernel slots
    const size_t spatial = ((size_t)d * H_ + h) * W_ + 4 * quad;

    float* o = out + ((size_t)(b * 4) * C_ + c) * dhw + spatial;
    __builtin_nontemporal_store(center, (float4v*)(o + 0 * cdhw));
    __builtin_nontemporal_store(sx,     (float4v*)(o + 1 * cdhw));
    __builtin_nontemporal_store(sy,     (float4v*)(o + 2 * cdhw));
    __builtin_nontemporal_store(sz,     (float4v*)(o + 3 * cdhw));
}

extern "C" void kernel_launch(void* const* d_in, const int* in_sizes, int n_in,
                              void* d_out, int out_size, void* d_ws, size_t ws_size,
                              hipStream_t stream) {
    (void)in_sizes; (void)n_in; (void)d_ws; (void)ws_size; (void)out_size;
    const float* x = (const float*)d_in[0];
    float* out = (float*)d_out;

    dim3 block(64, 4, 1);                  // wave = 16 w-quads x 4 h-rows
    dim3 grid(H_ / 16, D_, B_ * C_);       // 4 x 64 x 64 = 16384 blocks
    perceive3d_kernel<<<grid, block, 0, stream>>>(x, out);
}